// Round 10
// baseline (1013.087 us; speedup 1.0000x reference)
//
#include <hip/hip_runtime.h>
#include <hip/hip_bf16.h>

// Problem constants: B=8, T=12, N=80, C=12, HID=32, KS=3, KC=2, OH=6, ALPHA=3

// ---------------------------------------------------------------- pack weights
__global__ void k_pack(const float* __restrict__ eWg, const float* __restrict__ eWc,
                       const float* __restrict__ dWg, const float* __restrict__ dWc,
                       const float* __restrict__ W1, const float* __restrict__ b1,
                       const float* __restrict__ W2, const float* __restrict__ b2,
                       float* encWgh, float* encWch, float* WgX, float* WcX,
                       float* decWgc, float* decWcx, float* decWch, float* w12, float* c0) {
  int t = threadIdx.x;
  for (int idx = t; idx < 192*64; idx += 256) {
    int row = idx / 64, hh = idx % 64; int f = row / 32, ll = row % 32;
    encWgh[idx] = eWg[(f*33 + 1 + ll)*64 + hh];
    decWgc[idx] = dWg[(f*64 + ll)*64 + hh] + dWg[(f*64 + 32 + ll)*64 + hh];
  }
  for (int idx = t; idx < 192*32; idx += 256) {
    int row = idx / 32, hh = idx % 32; int f = row / 32, ll = row % 32;
    encWch[idx] = eWc[(f*33 + 1 + ll)*32 + hh];
    decWcx[idx] = dWc[(f*64 + ll)*32 + hh];
    decWch[idx] = dWc[(f*64 + 32 + ll)*32 + hh];
  }
  for (int idx = t; idx < 384; idx += 256) { int f = idx/64, hh = idx%64; WgX[idx] = eWg[(f*33)*64 + hh]; }
  if (t < 192) { int f = t/32, hh = t%32; WcX[t] = eWc[(f*33)*32 + hh]; }
  if (t < 32) { float s = 0; for (int j = 0; j < 16; ++j) s += W1[t*16+j]*W2[j]; w12[t] = s; }
  if (t == 0) { float s = 0; for (int j = 0; j < 16; ++j) s += b1[j]*W2[j]; c0[0] = s + b2[0]; }
}

// ---------------------------------------------------------------- Us/Vs + Uc/Vc merged
__global__ __launch_bounds__(256) void k_uv(const float* __restrict__ X,
                                            const float* __restrict__ WuS, const float* __restrict__ WvS,
                                            const float* __restrict__ WuC, const float* __restrict__ WvC,
                                            float* __restrict__ Us, float* __restrict__ Vs,
                                            float* __restrict__ Uc, float* __restrict__ Vc) {
  int t = threadIdx.x;
  int h = t & 31;
  if (blockIdx.x < 960) {                       // spatial: rows over B*T*N = 7680
    int row = blockIdx.x*8 + (t >> 5);
    const float* xr = X + (size_t)row*12;
    float su = 0.f, sv = 0.f;
#pragma unroll
    for (int c = 0; c < 12; ++c) {
      float x = xr[c];
      su += x*WuS[c*32+h]; sv += x*WvS[c*32+h];
    }
    Us[(size_t)row*32 + h] = tanhf(3.f*su);
    Vs[(size_t)row*32 + h] = tanhf(3.f*sv);
  } else {                                      // channel: rows over B*T*C = 1152
    int row = (blockIdx.x - 960)*8 + (t >> 5);
    int bt = row / 12, c = row % 12;
    const float* xb = X + (size_t)bt*960 + c;
    float su = 0.f, sv = 0.f;
    for (int n = 0; n < 80; ++n) {
      float x = xb[n*12];
      su += x*WuC[n*32+h]; sv += x*WvC[n*32+h];
    }
    Uc[(size_t)row*32 + h] = tanhf(3.f*su);
    Vc[(size_t)row*32 + h] = tanhf(3.f*sv);
  }
}

// ---------------------------------------------------------------- M (80x80) + Mc (12x12) merged
__global__ __launch_bounds__(256) void k_m_mc(const float* __restrict__ Us, const float* __restrict__ Vs,
                                              const float* __restrict__ Uc, const float* __restrict__ Vc,
                                              float* __restrict__ M, float* __restrict__ Mc) {
  __shared__ float su[8][16][33], sv[8][16][33];
  int t = threadIdx.x;
  if (blockIdx.x < 25) {
    int m0 = (blockIdx.x % 5)*16, n0 = (blockIdx.x / 5)*16;
    int tx = t & 15, ty = t >> 4;
    float acc = 0.f;
    for (int r0 = 0; r0 < 96; r0 += 8) {
      for (int idx = t; idx < 8*16*32; idx += 256) {
        int hh = idx & 31, i = (idx >> 5) & 15, rr = idx >> 9;
        su[rr][i][hh] = Us[((size_t)(r0+rr)*80 + n0 + i)*32 + hh];
        sv[rr][i][hh] = Vs[((size_t)(r0+rr)*80 + m0 + i)*32 + hh];
      }
      __syncthreads();
      for (int rr = 0; rr < 8; ++rr) {
#pragma unroll
        for (int hh = 0; hh < 32; ++hh) acc += su[rr][ty][hh] * sv[rr][tx][hh];
      }
      __syncthreads();
    }
    M[(n0+ty)*80 + (m0+tx)] = acc;
  } else {
    if (t < 144) {
      int c1 = t / 12, c2 = t % 12;
      float acc = 0.f;
      for (int r = 0; r < 96; ++r)
        for (int hh = 0; hh < 32; ++hh)
          acc += Uc[((size_t)r*12+c1)*32+hh] * Vc[((size_t)r*12+c2)*32+hh];
      Mc[t] = acc;
    }
  }
}

// ---------------------------------------------------------------- both softmaxes merged (92 rows)
__global__ void k_softmax2(const float* __restrict__ Ms, float* __restrict__ Ps,
                           const float* __restrict__ Mc, float* __restrict__ Pc) {
  int lane = threadIdx.x;      // block of 64
  const float* M; float* P; int row, n;
  if (blockIdx.x < 80) { M = Ms; P = Ps; row = blockIdx.x; n = 80; }
  else                 { M = Mc; P = Pc; row = blockIdx.x - 80; n = 12; }
  float v0 = -1e30f, v1 = -1e30f;
  {
    int m = lane;
    if (m < n) { float a = M[row*n + m] - M[m*n + row]; v0 = a > 0.f ? a : 0.f; }
    m = 64 + lane;
    if (m < n) { float a = M[row*n + m] - M[m*n + row]; v1 = a > 0.f ? a : 0.f; }
  }
  float mx = fmaxf(v0, v1);
  for (int off = 32; off; off >>= 1) mx = fmaxf(mx, __shfl_xor(mx, off));
  float s = 0.f;
  if (lane < n)      { v0 = expf(v0 - mx); s += v0; }
  if (64 + lane < n) { v1 = expf(v1 - mx); s += v1; }
  for (int off = 32; off; off >>= 1) s += __shfl_xor(s, off);
  float inv = 1.f / s;
  if (lane < n)      P[row*n + lane] = v0 * inv;
  if (64 + lane < n) P[row*n + 64 + lane] = v1 * inv;
}

// ---------------------------------------------------------------- fusion S partial (HBM-heavy)
// grid (25, 64), block (64,4); jb rotated per chunk to decorrelate column windows
__global__ __launch_bounds__(256) void k_fus_partial(
    const float* __restrict__ A, const float* __restrict__ P,
    const float* __restrict__ WA, const float* __restrict__ WP,
    float* __restrict__ part) {
  int lane = threadIdx.x, sub = threadIdx.y;   // (64,4)
  int jb = (blockIdx.x + blockIdx.y) % 25;     // rotate column slice per chunk
  int chunk = blockIdx.y;                      // (25,64)
  int j = jb*256 + lane*4;
  int i0 = chunk*100 + sub*25;
  float4 acc = {0.f, 0.f, 0.f, 0.f};
  for (int ii = 0; ii < 25; ii += 5) {
    float a[5], p[5]; float4 wa[5], wp[5];
#pragma unroll
    for (int u = 0; u < 5; ++u) {
      int i = i0 + ii + u;
      a[u] = A[i]; p[u] = P[i];
      wa[u] = *(const float4*)(WA + (size_t)i*6400 + j);
      wp[u] = *(const float4*)(WP + (size_t)i*6400 + j);
    }
#pragma unroll
    for (int u = 0; u < 5; ++u) {
      acc.x += a[u]*wa[u].x + p[u]*wp[u].x;
      acc.y += a[u]*wa[u].y + p[u]*wp[u].y;
      acc.z += a[u]*wa[u].z + p[u]*wp[u].z;
      acc.w += a[u]*wa[u].w + p[u]*wp[u].w;
    }
  }
  __shared__ float4 red[4][64];
  red[sub][lane] = acc;
  __syncthreads();
  if (sub == 0) {
    float4 r0 = red[0][lane], r1 = red[1][lane], r2 = red[2][lane], r3 = red[3][lane];
    float4 o = {r0.x+r1.x+r2.x+r3.x, r0.y+r1.y+r2.y+r3.y,
                r0.z+r1.z+r2.z+r3.z, r0.w+r1.w+r2.w+r3.w};
    *(float4*)(part + (size_t)chunk*6400 + j) = o;
  }
}

// ---------------------------------------------------------------- fus_final (S) + fusc (C) merged
__global__ void k_final2(const float* __restrict__ part,
                         const float* __restrict__ bA, const float* __restrict__ bP,
                         const float* __restrict__ A, const float* __restrict__ P,
                         float* __restrict__ G,
                         const float* __restrict__ Ac, const float* __restrict__ Pc,
                         const float* __restrict__ WA_C, const float* __restrict__ WP_C,
                         const float* __restrict__ bA_C, const float* __restrict__ bP_C,
                         float* __restrict__ Gc) {
  int t = threadIdx.x;
  if (blockIdx.x < 25) {
    int j = blockIdx.x*256 + t;
    float s = 0.f;
    for (int k = 0; k < 64; ++k) s += part[(size_t)k*6400 + j];
    s += bA[j] + bP[j];
    float a = 1.f / (1.f + expf(-s));
    G[j] = a*A[j] + (1.f - a)*P[j];
  } else if (t < 144) {
    float s = 0.f;
    for (int i = 0; i < 144; ++i) s += Ac[i]*WA_C[i*144+t] + Pc[i]*WP_C[i*144+t];
    s += bA_C[t] + bP_C[t];
    float a = 1.f / (1.f + expf(-s));
    Gc[t] = a*Ac[t] + (1.f - a)*Pc[t];
  }
}

// ---------------------------------------------------------------- Gs2 = 2*Gs@Gs - I
__global__ void k_cheby(const float* __restrict__ G, float* __restrict__ G2) {
  int j = blockIdx.x*256 + threadIdx.x;
  int n = j / 80, m = j % 80;
  float s = 0.f;
  for (int k = 0; k < 80; ++k) s += G[n*80+k]*G[k*80+m];
  G2[j] = 2.f*s - (n == m ? 1.f : 0.f);
}

// ---------------------------------------------------------------- precompute Xt field; t==0 blocks
// additionally compute H directly (encoder step 0 with H=0: H = sigmoid(gXg+bg)*tanh(gXc+bc)),
// replacing the separate k_cell0 dispatch and the H-zeroing.
__global__ __launch_bounds__(256) void k_gx(const float* __restrict__ X,
                                            const float* __restrict__ Gs, const float* __restrict__ Gs2,
                                            const float* __restrict__ Gc,
                                            const float* __restrict__ WgX, const float* __restrict__ WcX,
                                            const float* __restrict__ ebg, const float* __restrict__ ebc,
                                            float* __restrict__ gXg, float* __restrict__ gXc,
                                            float* __restrict__ H) {
  int bt = blockIdx.x, q = blockIdx.y, t = threadIdx.x;
  __shared__ float xl[960], xg1[240], xg2[240], S[240*6];
  for (int i = t; i < 960; i += 256) xl[i] = X[(size_t)bt*960 + i];
  __syncthreads();
  if (t < 240) {
    int nl = t / 12, c = t % 12, n = q*20 + nl;
    float s1 = 0.f, s2 = 0.f;
    for (int np = 0; np < 80; ++np) { float x = xl[np*12 + c]; s1 += Gs[np*80+n]*x; s2 += Gs2[np*80+n]*x; }
    xg1[t] = s1; xg2[t] = s2;
    S[t*6+0] = xl[n*12+c]; S[t*6+2] = s1; S[t*6+4] = s2;
  }
  __syncthreads();
  if (t < 240) {
    int nl = t / 12, c = t % 12, n = q*20 + nl;
    float a1 = 0.f, a3 = 0.f, a5 = 0.f;
    for (int cp = 0; cp < 12; ++cp) {
      float g = Gc[cp*12 + c];
      a1 += xl[n*12+cp]*g; a3 += xg1[nl*12+cp]*g; a5 += xg2[nl*12+cp]*g;
    }
    S[t*6+1] = a1; S[t*6+3] = a3; S[t*6+5] = a5;
  }
  __syncthreads();
  for (int idx = t; idx < 240*64; idx += 256) {
    int h = idx % 64, pair = idx / 64; int nl = pair/12, c = pair%12; int n = q*20+nl;
    float s = 0.f;
#pragma unroll
    for (int f = 0; f < 6; ++f) s += S[pair*6+f] * WgX[f*64+h];
    gXg[((size_t)bt*960 + n*12 + c)*64 + h] = s;
  }
  for (int idx = t; idx < 240*32; idx += 256) {
    int h = idx % 32, pair = idx / 32; int nl = pair/12, c = pair%12; int n = q*20+nl;
    float s = 0.f;
#pragma unroll
    for (int f = 0; f < 6; ++f) s += S[pair*6+f] * WcX[f*32+h];
    gXc[((size_t)bt*960 + n*12 + c)*32 + h] = s;
  }
  if (bt % 12 == 0) {      // t==0 timestep: compute encoder step-0 H directly
    int b = bt / 12;
    for (int idx = t; idx < 240*32; idx += 256) {
      int h = idx & 31, pair = idx >> 5; int nl = pair/12, c = pair%12; int n = q*20+nl;
      float sg = 0.f, sc = 0.f;
#pragma unroll
      for (int f = 0; f < 6; ++f) {
        float sv = S[pair*6+f];
        sg += sv*WgX[f*64+h];    // update gate = first 32 of the 64 gate outputs
        sc += sv*WcX[f*32+h];
      }
      float uu = 1.f / (1.f + expf(-(sg + ebg[h])));
      H[((size_t)(b*80) + n)*12*32 + (size_t)c*32 + h] = uu * tanhf(sc + ebc[h]);
    }
  }
}

// ---------------------------------------------------------------- generic GRU-cell bdg kernel
// R9-proven structure (256 threads, MT=2, grid (40,8), float4 phase-3, Gcol in LDS)
// + ONE change: phase-1 U reads staged through LDS (10 chunks x 8 nodes, double-
// buffered float4 staging) — 240 scalar L2-latency loads/thread -> 30 vector loads
// with latency hidden under the previous chunk's compute.
// MODE 0 (HOUT=64): outA=sigmoid(g[:32]) (update), outB=sigmoid(g[32:])*H (reset*H).
// MODE 1 (HOUT=32): outA=(1-upd)*H+upd*tanh(g); optional fused out-projection.
template<int HOUT, int MODE, bool HAS_U2, bool HAS_FIELD, bool DO_PROJ>
__global__ __launch_bounds__(256) void k_cell(
    const float* __restrict__ U1, const float* __restrict__ W1p,
    const float* __restrict__ U2, const float* __restrict__ W2p,
    const float* __restrict__ field, int fbs,
    const float* __restrict__ bias,
    const float* __restrict__ Gsd, const float* __restrict__ Gs2d, const float* __restrict__ Gcd,
    const float* Hbuf, const float* updbuf,
    float* outA, float* outB,
    const float* __restrict__ w12p, const float* __restrict__ c0p,
    float* projp, int step)
{
  constexpr int MT = 2;
  constexpr int NG = 256 / HOUT;          // pair groups per pass (4 or 8)
  constexpr int NP = (MT*12) / NG;        // passes (6 or 3)
  const int t = threadIdx.x;
  const int b = blockIdx.y;
  const int m0 = blockIdx.x * MT;
  __shared__ float fA[3*MT*384];          // [kn][m][c][l]
  __shared__ float fB[3*MT*384];          // [kn][m][d][l]  (·Gc)
  __shared__ float Gcol[320];             // [lev][mg][n]
  __shared__ float Ust[2][3072];          // double-buffered 8-node U chunks
  const int mg = t >> 7;                  // local m (0..1)
  const int u  = t & 127;
  const int c0 = u >> 5;                  // 0..3
  const int l  = u & 31;
  const int h  = t % HOUT;
  const int pg = t / HOUT;
  int bofs[NP];
#pragma unroll
  for (int p = 0; p < NP; ++p) bofs[p] = (p*NG + pg) * 32;
  float outr[NP];
#pragma unroll
  for (int p = 0; p < NP; ++p) outr[p] = 0.f;

  // stage G columns (m0, m0+1) for both Chebyshev levels
  for (int i = t; i < 320; i += 256) {
    int lev = i / 160, r = i % 160, mi = r / 80, n = r % 80;
    Gcol[i] = (lev ? Gs2d : Gsd)[n*80 + m0 + mi];
  }

  const size_t ub_base = (size_t)b*80*12*32;
  const int nrounds = HAS_U2 ? 2 : 1;
  for (int rnd = 0; rnd < nrounds; ++rnd) {
    const float* U  = rnd ? U2 : U1;
    const float* Wp = rnd ? W2p : W1p;
    const float* Ub = U + ub_base;
    if (rnd) __syncthreads();            // protect Ust/fA: prior round's readers done
    // ---- phase 1: mode-1 diffusion over N, U staged through LDS (double-buffered)
    {
      const float4* s4 = (const float4*)Ub;
      float4* d4 = (float4*)Ust[0];
      d4[t] = s4[t]; d4[t+256] = s4[t+256]; d4[t+512] = s4[t+512];
    }
    float a0[3], a1[3], a2[3];
#pragma unroll
    for (int j = 0; j < 3; ++j) { a1[j] = 0.f; a2[j] = 0.f; }
    for (int ch = 0; ch < 10; ++ch) {
      __syncthreads();                   // staged chunk ch visible
      if (ch < 9) {                      // issue next chunk's loads early (latency hides)
        const float4* s4 = (const float4*)(Ub + (ch+1)*3072);
        float4* d4 = (float4*)Ust[(ch+1) & 1];
        d4[t] = s4[t]; d4[t+256] = s4[t+256]; d4[t+512] = s4[t+512];
      }
      const float* Uc_ = Ust[ch & 1];
#pragma unroll
      for (int n8 = 0; n8 < 8; ++n8) {
        int n = ch*8 + n8;
        float g1 = Gcol[mg*80 + n];
        float g2 = Gcol[160 + mg*80 + n];
#pragma unroll
        for (int j = 0; j < 3; ++j) {
          float x = Uc_[n8*384 + (c0 + 4*j)*32 + l];
          a1[j] += g1*x; a2[j] += g2*x;
        }
      }
    }
#pragma unroll
    for (int j = 0; j < 3; ++j) a0[j] = Ub[((m0+mg)*12 + c0 + 4*j)*32 + l];
#pragma unroll
    for (int j = 0; j < 3; ++j) {
      int cc = c0 + 4*j;
      fA[(0*MT+mg)*384 + cc*32 + l] = a0[j];
      fA[(1*MT+mg)*384 + cc*32 + l] = a1[j];
      fA[(2*MT+mg)*384 + cc*32 + l] = a2[j];
    }
    __syncthreads();
    // ---- phase 2: mode-2 (·Gc along C)
    for (int idx = t; idx < 3*MT*384; idx += 256) {
      int ll = idx & 31;
      int d  = (idx >> 5) % 12;
      int km = idx / 384;
      float s = 0.f;
#pragma unroll
      for (int c = 0; c < 12; ++c) s += fA[km*384 + c*32 + ll] * Gcd[c*12 + d];
      fB[km*384 + d*32 + ll] = s;
    }
    __syncthreads();
    // ---- phase 3: feat @ Wp (register-blocked over NP pairs, float4 LDS reads)
    for (int f = 0; f < 6; ++f) {
      int kn = f >> 1;
      const float* src = ((f & 1) ? fB : fA) + kn*MT*384;
#pragma unroll
      for (int l4 = 0; l4 < 8; ++l4) {
        const float w0 = Wp[(f*32 + l4*4 + 0)*HOUT + h];
        const float w1 = Wp[(f*32 + l4*4 + 1)*HOUT + h];
        const float w2 = Wp[(f*32 + l4*4 + 2)*HOUT + h];
        const float w3 = Wp[(f*32 + l4*4 + 3)*HOUT + h];
#pragma unroll
        for (int p = 0; p < NP; ++p) {
          const float4 v = *(const float4*)&src[bofs[p] + l4*4];
          outr[p] += v.x*w0 + v.y*w1 + v.z*w2 + v.w*w3;
        }
      }
    }
  }
  // ---- epilogue
#pragma unroll
  for (int p = 0; p < NP; ++p) {
    int pair = p*NG + pg;
    int m = pair / 12, c = pair % 12;
    int n = m0 + m;
    size_t oidx = (size_t)(b*80 + n)*12 + c;
    float g = outr[p] + bias[h];
    if (HAS_FIELD) g += field[(size_t)b*fbs + (size_t)(n*12 + c)*HOUT + h];
    if (MODE == 0) {
      float sg = 1.f / (1.f + expf(-g));
      size_t hb = oidx*32;
      if (h < 32) outA[hb + h] = sg;                               // update
      else        outB[hb + (h-32)] = sg * Hbuf[hb + (h-32)];      // reset*H
    } else {
      float cd = tanhf(g);
      size_t hi = oidx*32 + h;
      float uu = updbuf[hi];
      float hv = Hbuf[hi];
      float hn = (1.f - uu)*hv + uu*cd;
      outA[hi] = hn;
      if (DO_PROJ) {
        float pv = hn * w12p[h];
        for (int off = 16; off; off >>= 1) pv += __shfl_down(pv, off, 32);
        if (h == 0) projp[((size_t)(b*6 + step)*80 + n)*12 + c] = pv + c0p[0];
      }
    }
  }
}

// ================================================================= host
extern "C" void kernel_launch(void* const* d_in, const int* in_sizes, int n_in,
                              void* d_out, int out_size, void* d_ws, size_t ws_size,
                              hipStream_t stream) {
  (void)in_sizes; (void)n_in; (void)out_size;
  const float* X    = (const float*)d_in[0];
  const float* As   = (const float*)d_in[1];
  const float* Ac   = (const float*)d_in[2];
  const float* WuS  = (const float*)d_in[3];
  const float* WvS  = (const float*)d_in[4];
  const float* WuC  = (const float*)d_in[5];
  const float* WvC  = (const float*)d_in[6];
  const float* WA_S = (const float*)d_in[7];
  const float* bA_S = (const float*)d_in[8];
  const float* WP_S = (const float*)d_in[9];
  const float* bP_S = (const float*)d_in[10];
  const float* WA_C = (const float*)d_in[11];
  const float* bA_C = (const float*)d_in[12];
  const float* WP_C = (const float*)d_in[13];
  const float* bP_C = (const float*)d_in[14];
  const float* eWg  = (const float*)d_in[15];
  const float* ebg  = (const float*)d_in[16];
  const float* eWc  = (const float*)d_in[17];
  const float* ebc  = (const float*)d_in[18];
  const float* dWg  = (const float*)d_in[19];
  const float* dbg  = (const float*)d_in[20];
  const float* dWc  = (const float*)d_in[21];
  const float* dbc  = (const float*)d_in[22];
  const float* W1   = (const float*)d_in[23];
  const float* b1   = (const float*)d_in[24];
  const float* W2   = (const float*)d_in[25];
  const float* b2   = (const float*)d_in[26];
  float* out = (float*)d_out;

  float* w = (float*)d_ws;
  size_t o = 0;
  auto alloc = [&](size_t n) { float* p = w + o; o += (n + 63) & ~(size_t)63; return p; };
  float* Us     = alloc(245760);
  float* Vs     = alloc(245760);
  float* Uc     = alloc(36864);
  float* Vc     = alloc(36864);
  float* Mb     = alloc(6400);
  float* Mc     = alloc(144);
  float* Ps     = alloc(6400);
  float* Pc     = alloc(144);
  float* part   = alloc((size_t)64*6400);
  float* Gs     = alloc(6400);
  float* Gc     = alloc(144);
  float* Gs2    = alloc(6400);
  float* encWgh = alloc(192*64);
  float* encWch = alloc(192*32);
  float* WgX    = alloc(384);
  float* WcX    = alloc(192);
  float* decWgc = alloc(192*64);
  float* decWcx = alloc(192*32);
  float* decWch = alloc(192*32);
  float* w12    = alloc(32);
  float* c0     = alloc(64);
  float* H      = alloc(245760);
  float* H2     = alloc(245760);
  float* upd    = alloc(245760);
  float* rH     = alloc(245760);
  float* gXg    = alloc((size_t)5898240);
  float* gXc    = alloc((size_t)2949120);
  if (o * sizeof(float) > ws_size) return;   // insufficient scratch -> fail loudly

  k_pack<<<1,256,0,stream>>>(eWg, eWc, dWg, dWc, W1, b1, W2, b2,
                             encWgh, encWch, WgX, WcX, decWgc, decWcx, decWch, w12, c0);
  k_uv<<<1104,256,0,stream>>>(X, WuS, WvS, WuC, WvC, Us, Vs, Uc, Vc);
  k_m_mc<<<26,256,0,stream>>>(Us, Vs, Uc, Vc, Mb, Mc);
  k_softmax2<<<92,64,0,stream>>>(Mb, Ps, Mc, Pc);
  k_fus_partial<<<dim3(25,64),dim3(64,4),0,stream>>>(As, Ps, WA_S, WP_S, part);
  k_final2<<<26,256,0,stream>>>(part, bA_S, bP_S, As, Ps, Gs,
                                Ac, Pc, WA_C, WP_C, bA_C, bP_C, Gc);
  k_cheby<<<25,256,0,stream>>>(Gs, Gs2);
  // k_gx also computes encoder step-0 H in its t==0 blocks (replaces k_cell0 + H memset)
  k_gx<<<dim3(96,4),256,0,stream>>>(X, Gs, Gs2, Gc, WgX, WcX, ebg, ebc, gXg, gXc, H);

  // encoder steps 1..11: H updated in place (cand reads H only pointwise)
  for (int t = 1; t < 12; ++t) {
    k_cell<64,0,false,true,false><<<dim3(40,8),256,0,stream>>>(
        H, encWgh, nullptr, nullptr, gXg + (size_t)t*61440, 737280, ebg,
        Gs, Gs2, Gc, H, nullptr, upd, rH, nullptr, nullptr, nullptr, 0);
    k_cell<32,1,false,true,false><<<dim3(40,8),256,0,stream>>>(
        rH, encWch, nullptr, nullptr, gXc + (size_t)t*30720, 368640, ebc,
        Gs, Gs2, Gc, H, upd, H, nullptr, nullptr, nullptr, nullptr, 0);
  }
  // decoder: 6 steps, Xin == H (combined gate weights), ping-pong buffers
  float* Hd = H; float* Hn = H2;
  for (int i = 0; i < 6; ++i) {
    k_cell<64,0,false,false,false><<<dim3(40,8),256,0,stream>>>(
        Hd, decWgc, nullptr, nullptr, nullptr, 0, dbg,
        Gs, Gs2, Gc, Hd, nullptr, upd, rH, nullptr, nullptr, nullptr, 0);
    k_cell<32,1,true,false,true><<<dim3(40,8),256,0,stream>>>(
        Hd, decWcx, rH, decWch, nullptr, 0, dbc,
        Gs, Gs2, Gc, Hd, upd, Hn, nullptr, w12, c0, out, i);
    float* tmp = Hd; Hd = Hn; Hn = tmp;
  }
}

// Round 12
// 953.957 us; speedup vs baseline: 1.0620x; 1.0620x over previous
//
#include <hip/hip_runtime.h>
#include <hip/hip_bf16.h>

// Problem constants: B=8, T=12, N=80, C=12, HID=32, KS=3, KC=2, OH=6, ALPHA=3

typedef float nt4 __attribute__((ext_vector_type(4)));   // native vector for nontemporal builtins

// ---------------------------------------------------------------- pack weights
__global__ void k_pack(const float* __restrict__ eWg, const float* __restrict__ eWc,
                       const float* __restrict__ dWg, const float* __restrict__ dWc,
                       const float* __restrict__ W1, const float* __restrict__ b1,
                       const float* __restrict__ W2, const float* __restrict__ b2,
                       float* encWgh, float* encWch, float* WgX, float* WcX,
                       float* decWgc, float* decWcx, float* decWch, float* w12, float* c0) {
  int t = threadIdx.x;
  for (int idx = t; idx < 192*64; idx += 256) {
    int row = idx / 64, hh = idx % 64; int f = row / 32, ll = row % 32;
    encWgh[idx] = eWg[(f*33 + 1 + ll)*64 + hh];
    decWgc[idx] = dWg[(f*64 + ll)*64 + hh] + dWg[(f*64 + 32 + ll)*64 + hh];
  }
  for (int idx = t; idx < 192*32; idx += 256) {
    int row = idx / 32, hh = idx % 32; int f = row / 32, ll = row % 32;
    encWch[idx] = eWc[(f*33 + 1 + ll)*32 + hh];
    decWcx[idx] = dWc[(f*64 + ll)*32 + hh];
    decWch[idx] = dWc[(f*64 + 32 + ll)*32 + hh];
  }
  for (int idx = t; idx < 384; idx += 256) { int f = idx/64, hh = idx%64; WgX[idx] = eWg[(f*33)*64 + hh]; }
  if (t < 192) { int f = t/32, hh = t%32; WcX[t] = eWc[(f*33)*32 + hh]; }
  if (t < 32) { float s = 0; for (int j = 0; j < 16; ++j) s += W1[t*16+j]*W2[j]; w12[t] = s; }
  if (t == 0) { float s = 0; for (int j = 0; j < 16; ++j) s += b1[j]*W2[j]; c0[0] = s + b2[0]; }
}

// ---------------------------------------------------------------- Us/Vs + Uc/Vc merged
__global__ __launch_bounds__(256) void k_uv(const float* __restrict__ X,
                                            const float* __restrict__ WuS, const float* __restrict__ WvS,
                                            const float* __restrict__ WuC, const float* __restrict__ WvC,
                                            float* __restrict__ Us, float* __restrict__ Vs,
                                            float* __restrict__ Uc, float* __restrict__ Vc) {
  int t = threadIdx.x;
  int h = t & 31;
  if (blockIdx.x < 960) {                       // spatial: rows over B*T*N = 7680
    int row = blockIdx.x*8 + (t >> 5);
    const float* xr = X + (size_t)row*12;
    float su = 0.f, sv = 0.f;
#pragma unroll
    for (int c = 0; c < 12; ++c) {
      float x = xr[c];
      su += x*WuS[c*32+h]; sv += x*WvS[c*32+h];
    }
    Us[(size_t)row*32 + h] = tanhf(3.f*su);
    Vs[(size_t)row*32 + h] = tanhf(3.f*sv);
  } else {                                      // channel: rows over B*T*C = 1152
    int row = (blockIdx.x - 960)*8 + (t >> 5);
    int bt = row / 12, c = row % 12;
    const float* xb = X + (size_t)bt*960 + c;
    float su = 0.f, sv = 0.f;
    for (int n = 0; n < 80; ++n) {
      float x = xb[n*12];
      su += x*WuC[n*32+h]; sv += x*WvC[n*32+h];
    }
    Uc[(size_t)row*32 + h] = tanhf(3.f*su);
    Vc[(size_t)row*32 + h] = tanhf(3.f*sv);
  }
}

// ---------------------------------------------------------------- M (80x80) + Mc (12x12) merged
__global__ __launch_bounds__(256) void k_m_mc(const float* __restrict__ Us, const float* __restrict__ Vs,
                                              const float* __restrict__ Uc, const float* __restrict__ Vc,
                                              float* __restrict__ M, float* __restrict__ Mc) {
  __shared__ float su[8][16][33], sv[8][16][33];
  int t = threadIdx.x;
  if (blockIdx.x < 25) {
    int m0 = (blockIdx.x % 5)*16, n0 = (blockIdx.x / 5)*16;
    int tx = t & 15, ty = t >> 4;
    float acc = 0.f;
    for (int r0 = 0; r0 < 96; r0 += 8) {
      for (int idx = t; idx < 8*16*32; idx += 256) {
        int hh = idx & 31, i = (idx >> 5) & 15, rr = idx >> 9;
        su[rr][i][hh] = Us[((size_t)(r0+rr)*80 + n0 + i)*32 + hh];
        sv[rr][i][hh] = Vs[((size_t)(r0+rr)*80 + m0 + i)*32 + hh];
      }
      __syncthreads();
      for (int rr = 0; rr < 8; ++rr) {
#pragma unroll
        for (int hh = 0; hh < 32; ++hh) acc += su[rr][ty][hh] * sv[rr][tx][hh];
      }
      __syncthreads();
    }
    M[(n0+ty)*80 + (m0+tx)] = acc;
  } else {
    if (t < 144) {
      int c1 = t / 12, c2 = t % 12;
      float acc = 0.f;
      for (int r = 0; r < 96; ++r)
        for (int hh = 0; hh < 32; ++hh)
          acc += Uc[((size_t)r*12+c1)*32+hh] * Vc[((size_t)r*12+c2)*32+hh];
      Mc[t] = acc;
    }
  }
}

// ---------------------------------------------------------------- both softmaxes merged (92 rows)
__global__ void k_softmax2(const float* __restrict__ Ms, float* __restrict__ Ps,
                           const float* __restrict__ Mc, float* __restrict__ Pc) {
  int lane = threadIdx.x;      // block of 64
  const float* M; float* P; int row, n;
  if (blockIdx.x < 80) { M = Ms; P = Ps; row = blockIdx.x; n = 80; }
  else                 { M = Mc; P = Pc; row = blockIdx.x - 80; n = 12; }
  float v0 = -1e30f, v1 = -1e30f;
  {
    int m = lane;
    if (m < n) { float a = M[row*n + m] - M[m*n + row]; v0 = a > 0.f ? a : 0.f; }
    m = 64 + lane;
    if (m < n) { float a = M[row*n + m] - M[m*n + row]; v1 = a > 0.f ? a : 0.f; }
  }
  float mx = fmaxf(v0, v1);
  for (int off = 32; off; off >>= 1) mx = fmaxf(mx, __shfl_xor(mx, off));
  float s = 0.f;
  if (lane < n)      { v0 = expf(v0 - mx); s += v0; }
  if (64 + lane < n) { v1 = expf(v1 - mx); s += v1; }
  for (int off = 32; off; off >>= 1) s += __shfl_xor(s, off);
  float inv = 1.f / s;
  if (lane < n)      P[row*n + lane] = v0 * inv;
  if (64 + lane < n) P[row*n + 64 + lane] = v1 * inv;
}

// ---------------------------------------------------------------- fusion S partial (HBM-heavy)
// grid (25, 64), block (64,4). Weight reads use NON-TEMPORAL loads (nt flag):
// zero intra-dispatch reuse, so bypassing L2/L3 lets the full 327 MB stream from
// HBM at streaming rate instead of being half-served by a thrashing L3.
__global__ __launch_bounds__(256) void k_fus_partial(
    const float* __restrict__ A, const float* __restrict__ P,
    const float* __restrict__ WA, const float* __restrict__ WP,
    float* __restrict__ part) {
  int lane = threadIdx.x, sub = threadIdx.y;   // (64,4)
  int jb = (blockIdx.x + blockIdx.y) % 25;     // rotate column slice per chunk
  int chunk = blockIdx.y;                      // (25,64)
  int j = jb*256 + lane*4;
  int i0 = chunk*100 + sub*25;
  float4 acc = {0.f, 0.f, 0.f, 0.f};
  for (int ii = 0; ii < 25; ii += 5) {
    float a[5], p[5]; nt4 wa[5], wp[5];
#pragma unroll
    for (int u = 0; u < 5; ++u) {
      int i = i0 + ii + u;
      a[u] = A[i]; p[u] = P[i];
      wa[u] = __builtin_nontemporal_load((const nt4*)(WA + (size_t)i*6400 + j));
      wp[u] = __builtin_nontemporal_load((const nt4*)(WP + (size_t)i*6400 + j));
    }
#pragma unroll
    for (int u = 0; u < 5; ++u) {
      acc.x += a[u]*wa[u].x + p[u]*wp[u].x;
      acc.y += a[u]*wa[u].y + p[u]*wp[u].y;
      acc.z += a[u]*wa[u].z + p[u]*wp[u].z;
      acc.w += a[u]*wa[u].w + p[u]*wp[u].w;
    }
  }
  __shared__ float4 red[4][64];
  red[sub][lane] = acc;
  __syncthreads();
  if (sub == 0) {
    float4 r0 = red[0][lane], r1 = red[1][lane], r2 = red[2][lane], r3 = red[3][lane];
    float4 o = {r0.x+r1.x+r2.x+r3.x, r0.y+r1.y+r2.y+r3.y,
                r0.z+r1.z+r2.z+r3.z, r0.w+r1.w+r2.w+r3.w};
    *(float4*)(part + (size_t)chunk*6400 + j) = o;
  }
}

// ---------------------------------------------------------------- fus_final (S) + fusc (C) merged
__global__ void k_final2(const float* __restrict__ part,
                         const float* __restrict__ bA, const float* __restrict__ bP,
                         const float* __restrict__ A, const float* __restrict__ P,
                         float* __restrict__ G,
                         const float* __restrict__ Ac, const float* __restrict__ Pc,
                         const float* __restrict__ WA_C, const float* __restrict__ WP_C,
                         const float* __restrict__ bA_C, const float* __restrict__ bP_C,
                         float* __restrict__ Gc) {
  int t = threadIdx.x;
  if (blockIdx.x < 25) {
    int j = blockIdx.x*256 + t;
    float s = 0.f;
    for (int k = 0; k < 64; ++k) s += part[(size_t)k*6400 + j];
    s += bA[j] + bP[j];
    float a = 1.f / (1.f + expf(-s));
    G[j] = a*A[j] + (1.f - a)*P[j];
  } else if (t < 144) {
    float s = 0.f;
    for (int i = 0; i < 144; ++i) s += Ac[i]*WA_C[i*144+t] + Pc[i]*WP_C[i*144+t];
    s += bA_C[t] + bP_C[t];
    float a = 1.f / (1.f + expf(-s));
    Gc[t] = a*Ac[t] + (1.f - a)*Pc[t];
  }
}

// ---------------------------------------------------------------- Gs2 = 2*Gs@Gs - I
__global__ void k_cheby(const float* __restrict__ G, float* __restrict__ G2) {
  int j = blockIdx.x*256 + threadIdx.x;
  int n = j / 80, m = j % 80;
  float s = 0.f;
  for (int k = 0; k < 80; ++k) s += G[n*80+k]*G[k*80+m];
  G2[j] = 2.f*s - (n == m ? 1.f : 0.f);
}

// ---------------------------------------------------------------- precompute Xt field; t==0 blocks
// additionally compute H directly (encoder step 0 with H=0: H = sigmoid(gXg+bg)*tanh(gXc+bc)),
// replacing the separate k_cell0 dispatch and the H-zeroing.
__global__ __launch_bounds__(256) void k_gx(const float* __restrict__ X,
                                            const float* __restrict__ Gs, const float* __restrict__ Gs2,
                                            const float* __restrict__ Gc,
                                            const float* __restrict__ WgX, const float* __restrict__ WcX,
                                            const float* __restrict__ ebg, const float* __restrict__ ebc,
                                            float* __restrict__ gXg, float* __restrict__ gXc,
                                            float* __restrict__ H) {
  int bt = blockIdx.x, q = blockIdx.y, t = threadIdx.x;
  __shared__ float xl[960], xg1[240], xg2[240], S[240*6];
  for (int i = t; i < 960; i += 256) xl[i] = X[(size_t)bt*960 + i];
  __syncthreads();
  if (t < 240) {
    int nl = t / 12, c = t % 12, n = q*20 + nl;
    float s1 = 0.f, s2 = 0.f;
    for (int np = 0; np < 80; ++np) { float x = xl[np*12 + c]; s1 += Gs[np*80+n]*x; s2 += Gs2[np*80+n]*x; }
    xg1[t] = s1; xg2[t] = s2;
    S[t*6+0] = xl[n*12+c]; S[t*6+2] = s1; S[t*6+4] = s2;
  }
  __syncthreads();
  if (t < 240) {
    int nl = t / 12, c = t % 12, n = q*20 + nl;
    float a1 = 0.f, a3 = 0.f, a5 = 0.f;
    for (int cp = 0; cp < 12; ++cp) {
      float g = Gc[cp*12 + c];
      a1 += xl[n*12+cp]*g; a3 += xg1[nl*12+cp]*g; a5 += xg2[nl*12+cp]*g;
    }
    S[t*6+1] = a1; S[t*6+3] = a3; S[t*6+5] = a5;
  }
  __syncthreads();
  for (int idx = t; idx < 240*64; idx += 256) {
    int h = idx % 64, pair = idx / 64; int nl = pair/12, c = pair%12; int n = q*20+nl;
    float s = 0.f;
#pragma unroll
    for (int f = 0; f < 6; ++f) s += S[pair*6+f] * WgX[f*64+h];
    gXg[((size_t)bt*960 + n*12 + c)*64 + h] = s;
  }
  for (int idx = t; idx < 240*32; idx += 256) {
    int h = idx % 32, pair = idx / 32; int nl = pair/12, c = pair%12; int n = q*20+nl;
    float s = 0.f;
#pragma unroll
    for (int f = 0; f < 6; ++f) s += S[pair*6+f] * WcX[f*32+h];
    gXc[((size_t)bt*960 + n*12 + c)*32 + h] = s;
  }
  if (bt % 12 == 0) {      // t==0 timestep: compute encoder step-0 H directly
    int b = bt / 12;
    for (int idx = t; idx < 240*32; idx += 256) {
      int h = idx & 31, pair = idx >> 5; int nl = pair/12, c = pair%12; int n = q*20+nl;
      float sg = 0.f, sc = 0.f;
#pragma unroll
      for (int f = 0; f < 6; ++f) {
        float sv = S[pair*6+f];
        sg += sv*WgX[f*64+h];    // update gate = first 32 of the 64 gate outputs
        sc += sv*WcX[f*32+h];
      }
      float uu = 1.f / (1.f + expf(-(sg + ebg[h])));
      H[((size_t)(b*80) + n)*12*32 + (size_t)c*32 + h] = uu * tanhf(sc + ebc[h]);
    }
  }
}

// ---------------------------------------------------------------- generic GRU-cell bdg kernel
// Exact R9 structure (256 threads, MT=2, grid (40,8), Gcol staged in LDS, float4
// phase-3 LDS reads, direct global U loads in phase-1). R10's U-LDS staging reverted
// (the 10 extra barriers per round cost ~1.2 us/cell).
// MODE 0 (HOUT=64): outA=sigmoid(g[:32]) (update), outB=sigmoid(g[32:])*H (reset*H).
// MODE 1 (HOUT=32): outA=(1-upd)*H+upd*tanh(g); optional fused out-projection.
template<int HOUT, int MODE, bool HAS_U2, bool HAS_FIELD, bool DO_PROJ>
__global__ __launch_bounds__(256) void k_cell(
    const float* __restrict__ U1, const float* __restrict__ W1p,
    const float* __restrict__ U2, const float* __restrict__ W2p,
    const float* __restrict__ field, int fbs,
    const float* __restrict__ bias,
    const float* __restrict__ Gsd, const float* __restrict__ Gs2d, const float* __restrict__ Gcd,
    const float* Hbuf, const float* updbuf,
    float* outA, float* outB,
    const float* __restrict__ w12p, const float* __restrict__ c0p,
    float* projp, int step)
{
  constexpr int MT = 2;
  constexpr int NG = 256 / HOUT;          // pair groups per pass (4 or 8)
  constexpr int NP = (MT*12) / NG;        // passes (6 or 3)
  const int t = threadIdx.x;
  const int b = blockIdx.y;
  const int m0 = blockIdx.x * MT;
  __shared__ float fA[3*MT*384];          // [kn][m][c][l]
  __shared__ float fB[3*MT*384];          // [kn][m][d][l]  (·Gc)
  __shared__ float Gcol[320];             // [lev][mg][n]
  const int mg = t >> 7;                  // local m (0..1)
  const int u  = t & 127;
  const int c0 = u >> 5;                  // 0..3
  const int l  = u & 31;
  const int h  = t % HOUT;
  const int pg = t / HOUT;
  int bofs[NP];
#pragma unroll
  for (int p = 0; p < NP; ++p) bofs[p] = (p*NG + pg) * 32;
  float outr[NP];
#pragma unroll
  for (int p = 0; p < NP; ++p) outr[p] = 0.f;

  // stage G columns (m0, m0+1) for both Chebyshev levels
  for (int i = t; i < 320; i += 256) {
    int lev = i / 160, r = i % 160, mi = r / 80, n = r % 80;
    Gcol[i] = (lev ? Gs2d : Gsd)[n*80 + m0 + mi];
  }
  __syncthreads();

  const size_t ub_base = (size_t)b*80*12*32;
  const int nrounds = HAS_U2 ? 2 : 1;
  for (int rnd = 0; rnd < nrounds; ++rnd) {
    const float* U  = rnd ? U2 : U1;
    const float* Wp = rnd ? W2p : W1p;
    if (rnd) __syncthreads();            // protect LDS: prior phase-3 readers done
    // ---- phase 1: mode-1 diffusion over N into registers (G from LDS broadcast)
    float a0[3], a1[3], a2[3];
#pragma unroll
    for (int j = 0; j < 3; ++j) { a1[j] = 0.f; a2[j] = 0.f; }
    const float* Ub = U + ub_base;
    for (int n = 0; n < 80; ++n) {
      float g1 = Gcol[mg*80 + n];
      float g2 = Gcol[160 + mg*80 + n];
#pragma unroll
      for (int j = 0; j < 3; ++j) {
        float x = Ub[(n*12 + c0 + 4*j)*32 + l];
        a1[j] += g1*x; a2[j] += g2*x;
      }
    }
#pragma unroll
    for (int j = 0; j < 3; ++j) a0[j] = Ub[((m0+mg)*12 + c0 + 4*j)*32 + l];
#pragma unroll
    for (int j = 0; j < 3; ++j) {
      int cc = c0 + 4*j;
      fA[(0*MT+mg)*384 + cc*32 + l] = a0[j];
      fA[(1*MT+mg)*384 + cc*32 + l] = a1[j];
      fA[(2*MT+mg)*384 + cc*32 + l] = a2[j];
    }
    __syncthreads();
    // ---- phase 2: mode-2 (·Gc along C)
    for (int idx = t; idx < 3*MT*384; idx += 256) {
      int ll = idx & 31;
      int d  = (idx >> 5) % 12;
      int km = idx / 384;
      float s = 0.f;
#pragma unroll
      for (int c = 0; c < 12; ++c) s += fA[km*384 + c*32 + ll] * Gcd[c*12 + d];
      fB[km*384 + d*32 + ll] = s;
    }
    __syncthreads();
    // ---- phase 3: feat @ Wp (register-blocked over NP pairs, float4 LDS reads)
    for (int f = 0; f < 6; ++f) {
      int kn = f >> 1;
      const float* src = ((f & 1) ? fB : fA) + kn*MT*384;
#pragma unroll
      for (int l4 = 0; l4 < 8; ++l4) {
        const float w0 = Wp[(f*32 + l4*4 + 0)*HOUT + h];
        const float w1 = Wp[(f*32 + l4*4 + 1)*HOUT + h];
        const float w2 = Wp[(f*32 + l4*4 + 2)*HOUT + h];
        const float w3 = Wp[(f*32 + l4*4 + 3)*HOUT + h];
#pragma unroll
        for (int p = 0; p < NP; ++p) {
          const float4 v = *(const float4*)&src[bofs[p] + l4*4];
          outr[p] += v.x*w0 + v.y*w1 + v.z*w2 + v.w*w3;
        }
      }
    }
  }
  // ---- epilogue
#pragma unroll
  for (int p = 0; p < NP; ++p) {
    int pair = p*NG + pg;
    int m = pair / 12, c = pair % 12;
    int n = m0 + m;
    size_t oidx = (size_t)(b*80 + n)*12 + c;
    float g = outr[p] + bias[h];
    if (HAS_FIELD) g += field[(size_t)b*fbs + (size_t)(n*12 + c)*HOUT + h];
    if (MODE == 0) {
      float sg = 1.f / (1.f + expf(-g));
      size_t hb = oidx*32;
      if (h < 32) outA[hb + h] = sg;                               // update
      else        outB[hb + (h-32)] = sg * Hbuf[hb + (h-32)];      // reset*H
    } else {
      float cd = tanhf(g);
      size_t hi = oidx*32 + h;
      float uu = updbuf[hi];
      float hv = Hbuf[hi];
      float hn = (1.f - uu)*hv + uu*cd;
      outA[hi] = hn;
      if (DO_PROJ) {
        float pv = hn * w12p[h];
        for (int off = 16; off; off >>= 1) pv += __shfl_down(pv, off, 32);
        if (h == 0) projp[((size_t)(b*6 + step)*80 + n)*12 + c] = pv + c0p[0];
      }
    }
  }
}

// ================================================================= host
extern "C" void kernel_launch(void* const* d_in, const int* in_sizes, int n_in,
                              void* d_out, int out_size, void* d_ws, size_t ws_size,
                              hipStream_t stream) {
  (void)in_sizes; (void)n_in; (void)out_size;
  const float* X    = (const float*)d_in[0];
  const float* As   = (const float*)d_in[1];
  const float* Ac   = (const float*)d_in[2];
  const float* WuS  = (const float*)d_in[3];
  const float* WvS  = (const float*)d_in[4];
  const float* WuC  = (const float*)d_in[5];
  const float* WvC  = (const float*)d_in[6];
  const float* WA_S = (const float*)d_in[7];
  const float* bA_S = (const float*)d_in[8];
  const float* WP_S = (const float*)d_in[9];
  const float* bP_S = (const float*)d_in[10];
  const float* WA_C = (const float*)d_in[11];
  const float* bA_C = (const float*)d_in[12];
  const float* WP_C = (const float*)d_in[13];
  const float* bP_C = (const float*)d_in[14];
  const float* eWg  = (const float*)d_in[15];
  const float* ebg  = (const float*)d_in[16];
  const float* eWc  = (const float*)d_in[17];
  const float* ebc  = (const float*)d_in[18];
  const float* dWg  = (const float*)d_in[19];
  const float* dbg  = (const float*)d_in[20];
  const float* dWc  = (const float*)d_in[21];
  const float* dbc  = (const float*)d_in[22];
  const float* W1   = (const float*)d_in[23];
  const float* b1   = (const float*)d_in[24];
  const float* W2   = (const float*)d_in[25];
  const float* b2   = (const float*)d_in[26];
  float* out = (float*)d_out;

  float* w = (float*)d_ws;
  size_t o = 0;
  auto alloc = [&](size_t n) { float* p = w + o; o += (n + 63) & ~(size_t)63; return p; };
  float* Us     = alloc(245760);
  float* Vs     = alloc(245760);
  float* Uc     = alloc(36864);
  float* Vc     = alloc(36864);
  float* Mb     = alloc(6400);
  float* Mc     = alloc(144);
  float* Ps     = alloc(6400);
  float* Pc     = alloc(144);
  float* part   = alloc((size_t)64*6400);
  float* Gs     = alloc(6400);
  float* Gc     = alloc(144);
  float* Gs2    = alloc(6400);
  float* encWgh = alloc(192*64);
  float* encWch = alloc(192*32);
  float* WgX    = alloc(384);
  float* WcX    = alloc(192);
  float* decWgc = alloc(192*64);
  float* decWcx = alloc(192*32);
  float* decWch = alloc(192*32);
  float* w12    = alloc(32);
  float* c0     = alloc(64);
  float* H      = alloc(245760);
  float* H2     = alloc(245760);
  float* upd    = alloc(245760);
  float* rH     = alloc(245760);
  float* gXg    = alloc((size_t)5898240);
  float* gXc    = alloc((size_t)2949120);
  if (o * sizeof(float) > ws_size) return;   // insufficient scratch -> fail loudly

  k_pack<<<1,256,0,stream>>>(eWg, eWc, dWg, dWc, W1, b1, W2, b2,
                             encWgh, encWch, WgX, WcX, decWgc, decWcx, decWch, w12, c0);
  k_uv<<<1104,256,0,stream>>>(X, WuS, WvS, WuC, WvC, Us, Vs, Uc, Vc);
  k_m_mc<<<26,256,0,stream>>>(Us, Vs, Uc, Vc, Mb, Mc);
  k_softmax2<<<92,64,0,stream>>>(Mb, Ps, Mc, Pc);
  k_fus_partial<<<dim3(25,64),dim3(64,4),0,stream>>>(As, Ps, WA_S, WP_S, part);
  k_final2<<<26,256,0,stream>>>(part, bA_S, bP_S, As, Ps, Gs,
                                Ac, Pc, WA_C, WP_C, bA_C, bP_C, Gc);
  k_cheby<<<25,256,0,stream>>>(Gs, Gs2);
  // k_gx also computes encoder step-0 H in its t==0 blocks (replaces k_cell0 + H memset)
  k_gx<<<dim3(96,4),256,0,stream>>>(X, Gs, Gs2, Gc, WgX, WcX, ebg, ebc, gXg, gXc, H);

  // encoder steps 1..11: H updated in place (cand reads H only pointwise)
  for (int t = 1; t < 12; ++t) {
    k_cell<64,0,false,true,false><<<dim3(40,8),256,0,stream>>>(
        H, encWgh, nullptr, nullptr, gXg + (size_t)t*61440, 737280, ebg,
        Gs, Gs2, Gc, H, nullptr, upd, rH, nullptr, nullptr, nullptr, 0);
    k_cell<32,1,false,true,false><<<dim3(40,8),256,0,stream>>>(
        rH, encWch, nullptr, nullptr, gXc + (size_t)t*30720, 368640, ebc,
        Gs, Gs2, Gc, H, upd, H, nullptr, nullptr, nullptr, nullptr, 0);
  }
  // decoder: 6 steps, Xin == H (combined gate weights), ping-pong buffers
  float* Hd = H; float* Hn = H2;
  for (int i = 0; i < 6; ++i) {
    k_cell<64,0,false,false,false><<<dim3(40,8),256,0,stream>>>(
        Hd, decWgc, nullptr, nullptr, nullptr, 0, dbg,
        Gs, Gs2, Gc, Hd, nullptr, upd, rH, nullptr, nullptr, nullptr, 0);
    k_cell<32,1,true,false,true><<<dim3(40,8),256,0,stream>>>(
        Hd, decWcx, rH, decWch, nullptr, 0, dbc,
        Gs, Gs2, Gc, Hd, upd, Hn, nullptr, w12, c0, out, i);
    float* tmp = Hd; Hd = Hn; Hn = tmp;
  }
}

// Round 13
// 893.715 us; speedup vs baseline: 1.1336x; 1.0674x over previous
//
#include <hip/hip_runtime.h>
#include <hip/hip_bf16.h>

// Problem constants: B=8, T=12, N=80, C=12, HID=32, KS=3, KC=2, OH=6, ALPHA=3

typedef float nt4 __attribute__((ext_vector_type(4)));   // native vector for nontemporal builtins

// ---------------------------------------------------------------- pack weights
__global__ void k_pack(const float* __restrict__ eWg, const float* __restrict__ eWc,
                       const float* __restrict__ dWg, const float* __restrict__ dWc,
                       const float* __restrict__ W1, const float* __restrict__ b1,
                       const float* __restrict__ W2, const float* __restrict__ b2,
                       float* encWgh, float* encWch, float* WgX, float* WcX,
                       float* decWgc, float* decWcx, float* decWch, float* w12, float* c0) {
  int t = threadIdx.x;
  for (int idx = t; idx < 192*64; idx += 256) {
    int row = idx / 64, hh = idx % 64; int f = row / 32, ll = row % 32;
    encWgh[idx] = eWg[(f*33 + 1 + ll)*64 + hh];
    decWgc[idx] = dWg[(f*64 + ll)*64 + hh] + dWg[(f*64 + 32 + ll)*64 + hh];
  }
  for (int idx = t; idx < 192*32; idx += 256) {
    int row = idx / 32, hh = idx % 32; int f = row / 32, ll = row % 32;
    encWch[idx] = eWc[(f*33 + 1 + ll)*32 + hh];
    decWcx[idx] = dWc[(f*64 + ll)*32 + hh];
    decWch[idx] = dWc[(f*64 + 32 + ll)*32 + hh];
  }
  for (int idx = t; idx < 384; idx += 256) { int f = idx/64, hh = idx%64; WgX[idx] = eWg[(f*33)*64 + hh]; }
  if (t < 192) { int f = t/32, hh = t%32; WcX[t] = eWc[(f*33)*32 + hh]; }
  if (t < 32) { float s = 0; for (int j = 0; j < 16; ++j) s += W1[t*16+j]*W2[j]; w12[t] = s; }
  if (t == 0) { float s = 0; for (int j = 0; j < 16; ++j) s += b1[j]*W2[j]; c0[0] = s + b2[0]; }
}

// ---------------------------------------------------------------- Us/Vs + Uc/Vc merged
__global__ __launch_bounds__(256) void k_uv(const float* __restrict__ X,
                                            const float* __restrict__ WuS, const float* __restrict__ WvS,
                                            const float* __restrict__ WuC, const float* __restrict__ WvC,
                                            float* __restrict__ Us, float* __restrict__ Vs,
                                            float* __restrict__ Uc, float* __restrict__ Vc) {
  int t = threadIdx.x;
  int h = t & 31;
  if (blockIdx.x < 960) {                       // spatial: rows over B*T*N = 7680
    int row = blockIdx.x*8 + (t >> 5);
    const float* xr = X + (size_t)row*12;
    float su = 0.f, sv = 0.f;
#pragma unroll
    for (int c = 0; c < 12; ++c) {
      float x = xr[c];
      su += x*WuS[c*32+h]; sv += x*WvS[c*32+h];
    }
    Us[(size_t)row*32 + h] = tanhf(3.f*su);
    Vs[(size_t)row*32 + h] = tanhf(3.f*sv);
  } else {                                      // channel: rows over B*T*C = 1152
    int row = (blockIdx.x - 960)*8 + (t >> 5);
    int bt = row / 12, c = row % 12;
    const float* xb = X + (size_t)bt*960 + c;
    float su = 0.f, sv = 0.f;
    for (int n = 0; n < 80; ++n) {
      float x = xb[n*12];
      su += x*WuC[n*32+h]; sv += x*WvC[n*32+h];
    }
    Uc[(size_t)row*32 + h] = tanhf(3.f*su);
    Vc[(size_t)row*32 + h] = tanhf(3.f*sv);
  }
}

// ---------------------------------------------------------------- M/Mc partials, r-split 6 ways
// grid (26, 6): bx<25 -> 16x16 M tile, r in [chunk*16, chunk*16+16); bx==25 -> Mc partial.
// Partials land in Mpart[chunk*6544 + idx] (reuses the fusion 'part' scratch; stream-ordered).
__global__ __launch_bounds__(256) void k_m_mc_part(const float* __restrict__ Us, const float* __restrict__ Vs,
                                                   const float* __restrict__ Uc, const float* __restrict__ Vc,
                                                   float* __restrict__ Mpart) {
  __shared__ float su[8][16][33], sv[8][16][33];
  int t = threadIdx.x;
  int chunk = blockIdx.y;
  int rbase = chunk*16;
  float* Mp = Mpart + (size_t)chunk*6544;
  if (blockIdx.x < 25) {
    int m0 = (blockIdx.x % 5)*16, n0 = (blockIdx.x / 5)*16;
    int tx = t & 15, ty = t >> 4;
    float acc = 0.f;
    for (int r0 = rbase; r0 < rbase + 16; r0 += 8) {
      for (int idx = t; idx < 8*16*32; idx += 256) {
        int hh = idx & 31, i = (idx >> 5) & 15, rr = idx >> 9;
        su[rr][i][hh] = Us[((size_t)(r0+rr)*80 + n0 + i)*32 + hh];
        sv[rr][i][hh] = Vs[((size_t)(r0+rr)*80 + m0 + i)*32 + hh];
      }
      __syncthreads();
      for (int rr = 0; rr < 8; ++rr) {
#pragma unroll
        for (int hh = 0; hh < 32; ++hh) acc += su[rr][ty][hh] * sv[rr][tx][hh];
      }
      __syncthreads();
    }
    Mp[(n0+ty)*80 + (m0+tx)] = acc;
  } else {
    if (t < 144) {
      int c1 = t / 12, c2 = t % 12;
      float acc = 0.f;
      for (int r = rbase; r < rbase + 16; ++r)
        for (int hh = 0; hh < 32; ++hh)
          acc += Uc[((size_t)r*12+c1)*32+hh] * Vc[((size_t)r*12+c2)*32+hh];
      Mp[6400 + t] = acc;
    }
  }
}

// ---------------------------------------------------------------- reduce 6 partials -> M, Mc
__global__ void k_mred(const float* __restrict__ Mpart, float* __restrict__ M, float* __restrict__ Mc) {
  int idx = blockIdx.x*256 + threadIdx.x;
  if (idx < 6544) {
    float s = 0.f;
#pragma unroll
    for (int k = 0; k < 6; ++k) s += Mpart[(size_t)k*6544 + idx];
    if (idx < 6400) M[idx] = s;
    else            Mc[idx - 6400] = s;
  }
}

// ---------------------------------------------------------------- both softmaxes merged (92 rows)
__global__ void k_softmax2(const float* __restrict__ Ms, float* __restrict__ Ps,
                           const float* __restrict__ Mc, float* __restrict__ Pc) {
  int lane = threadIdx.x;      // block of 64
  const float* M; float* P; int row, n;
  if (blockIdx.x < 80) { M = Ms; P = Ps; row = blockIdx.x; n = 80; }
  else                 { M = Mc; P = Pc; row = blockIdx.x - 80; n = 12; }
  float v0 = -1e30f, v1 = -1e30f;
  {
    int m = lane;
    if (m < n) { float a = M[row*n + m] - M[m*n + row]; v0 = a > 0.f ? a : 0.f; }
    m = 64 + lane;
    if (m < n) { float a = M[row*n + m] - M[m*n + row]; v1 = a > 0.f ? a : 0.f; }
  }
  float mx = fmaxf(v0, v1);
  for (int off = 32; off; off >>= 1) mx = fmaxf(mx, __shfl_xor(mx, off));
  float s = 0.f;
  if (lane < n)      { v0 = expf(v0 - mx); s += v0; }
  if (64 + lane < n) { v1 = expf(v1 - mx); s += v1; }
  for (int off = 32; off; off >>= 1) s += __shfl_xor(s, off);
  float inv = 1.f / s;
  if (lane < n)      P[row*n + lane] = v0 * inv;
  if (64 + lane < n) P[row*n + 64 + lane] = v1 * inv;
}

// ---------------------------------------------------------------- fusion S partial (HBM-heavy)
// grid (25, 64), block (64,4). Weight reads use NON-TEMPORAL loads: zero reuse, so
// bypassing L2/L3 streams the full 327 MB from HBM (confirmed win in R12).
__global__ __launch_bounds__(256) void k_fus_partial(
    const float* __restrict__ A, const float* __restrict__ P,
    const float* __restrict__ WA, const float* __restrict__ WP,
    float* __restrict__ part) {
  int lane = threadIdx.x, sub = threadIdx.y;   // (64,4)
  int jb = (blockIdx.x + blockIdx.y) % 25;     // rotate column slice per chunk
  int chunk = blockIdx.y;                      // (25,64)
  int j = jb*256 + lane*4;
  int i0 = chunk*100 + sub*25;
  float4 acc = {0.f, 0.f, 0.f, 0.f};
  for (int ii = 0; ii < 25; ii += 5) {
    float a[5], p[5]; nt4 wa[5], wp[5];
#pragma unroll
    for (int u = 0; u < 5; ++u) {
      int i = i0 + ii + u;
      a[u] = A[i]; p[u] = P[i];
      wa[u] = __builtin_nontemporal_load((const nt4*)(WA + (size_t)i*6400 + j));
      wp[u] = __builtin_nontemporal_load((const nt4*)(WP + (size_t)i*6400 + j));
    }
#pragma unroll
    for (int u = 0; u < 5; ++u) {
      acc.x += a[u]*wa[u].x + p[u]*wp[u].x;
      acc.y += a[u]*wa[u].y + p[u]*wp[u].y;
      acc.z += a[u]*wa[u].z + p[u]*wp[u].z;
      acc.w += a[u]*wa[u].w + p[u]*wp[u].w;
    }
  }
  __shared__ float4 red[4][64];
  red[sub][lane] = acc;
  __syncthreads();
  if (sub == 0) {
    float4 r0 = red[0][lane], r1 = red[1][lane], r2 = red[2][lane], r3 = red[3][lane];
    float4 o = {r0.x+r1.x+r2.x+r3.x, r0.y+r1.y+r2.y+r3.y,
                r0.z+r1.z+r2.z+r3.z, r0.w+r1.w+r2.w+r3.w};
    *(float4*)(part + (size_t)chunk*6400 + j) = o;
  }
}

// ---------------------------------------------------------------- fus_final (S) + fusc (C) merged
__global__ void k_final2(const float* __restrict__ part,
                         const float* __restrict__ bA, const float* __restrict__ bP,
                         const float* __restrict__ A, const float* __restrict__ P,
                         float* __restrict__ G,
                         const float* __restrict__ Ac, const float* __restrict__ Pc,
                         const float* __restrict__ WA_C, const float* __restrict__ WP_C,
                         const float* __restrict__ bA_C, const float* __restrict__ bP_C,
                         float* __restrict__ Gc) {
  int t = threadIdx.x;
  if (blockIdx.x < 25) {
    int j = blockIdx.x*256 + t;
    float s = 0.f;
    for (int k = 0; k < 64; ++k) s += part[(size_t)k*6400 + j];
    s += bA[j] + bP[j];
    float a = 1.f / (1.f + expf(-s));
    G[j] = a*A[j] + (1.f - a)*P[j];
  } else if (t < 144) {
    float s = 0.f;
    for (int i = 0; i < 144; ++i) s += Ac[i]*WA_C[i*144+t] + Pc[i]*WP_C[i*144+t];
    s += bA_C[t] + bP_C[t];
    float a = 1.f / (1.f + expf(-s));
    Gc[t] = a*Ac[t] + (1.f - a)*Pc[t];
  }
}

// ---------------------------------------------------------------- Gs2 = 2*Gs@Gs - I
__global__ void k_cheby(const float* __restrict__ G, float* __restrict__ G2) {
  int j = blockIdx.x*256 + threadIdx.x;
  int n = j / 80, m = j % 80;
  float s = 0.f;
  for (int k = 0; k < 80; ++k) s += G[n*80+k]*G[k*80+m];
  G2[j] = 2.f*s - (n == m ? 1.f : 0.f);
}

// ---------------------------------------------------------------- precompute Xt field; t==0 blocks
// additionally compute H directly (encoder step 0 with H=0: H = sigmoid(gXg+bg)*tanh(gXc+bc)).
__global__ __launch_bounds__(256) void k_gx(const float* __restrict__ X,
                                            const float* __restrict__ Gs, const float* __restrict__ Gs2,
                                            const float* __restrict__ Gc,
                                            const float* __restrict__ WgX, const float* __restrict__ WcX,
                                            const float* __restrict__ ebg, const float* __restrict__ ebc,
                                            float* __restrict__ gXg, float* __restrict__ gXc,
                                            float* __restrict__ H) {
  int bt = blockIdx.x, q = blockIdx.y, t = threadIdx.x;
  __shared__ float xl[960], xg1[240], xg2[240], S[240*6];
  for (int i = t; i < 960; i += 256) xl[i] = X[(size_t)bt*960 + i];
  __syncthreads();
  if (t < 240) {
    int nl = t / 12, c = t % 12, n = q*20 + nl;
    float s1 = 0.f, s2 = 0.f;
    for (int np = 0; np < 80; ++np) { float x = xl[np*12 + c]; s1 += Gs[np*80+n]*x; s2 += Gs2[np*80+n]*x; }
    xg1[t] = s1; xg2[t] = s2;
    S[t*6+0] = xl[n*12+c]; S[t*6+2] = s1; S[t*6+4] = s2;
  }
  __syncthreads();
  if (t < 240) {
    int nl = t / 12, c = t % 12, n = q*20 + nl;
    float a1 = 0.f, a3 = 0.f, a5 = 0.f;
    for (int cp = 0; cp < 12; ++cp) {
      float g = Gc[cp*12 + c];
      a1 += xl[n*12+cp]*g; a3 += xg1[nl*12+cp]*g; a5 += xg2[nl*12+cp]*g;
    }
    S[t*6+1] = a1; S[t*6+3] = a3; S[t*6+5] = a5;
  }
  __syncthreads();
  for (int idx = t; idx < 240*64; idx += 256) {
    int h = idx % 64, pair = idx / 64; int nl = pair/12, c = pair%12; int n = q*20+nl;
    float s = 0.f;
#pragma unroll
    for (int f = 0; f < 6; ++f) s += S[pair*6+f] * WgX[f*64+h];
    gXg[((size_t)bt*960 + n*12 + c)*64 + h] = s;
  }
  for (int idx = t; idx < 240*32; idx += 256) {
    int h = idx % 32, pair = idx / 32; int nl = pair/12, c = pair%12; int n = q*20+nl;
    float s = 0.f;
#pragma unroll
    for (int f = 0; f < 6; ++f) s += S[pair*6+f] * WcX[f*32+h];
    gXc[((size_t)bt*960 + n*12 + c)*32 + h] = s;
  }
  if (bt % 12 == 0) {      // t==0 timestep: compute encoder step-0 H directly
    int b = bt / 12;
    for (int idx = t; idx < 240*32; idx += 256) {
      int h = idx & 31, pair = idx >> 5; int nl = pair/12, c = pair%12; int n = q*20+nl;
      float sg = 0.f, sc = 0.f;
#pragma unroll
      for (int f = 0; f < 6; ++f) {
        float sv = S[pair*6+f];
        sg += sv*WgX[f*64+h];    // update gate = first 32 of the 64 gate outputs
        sc += sv*WcX[f*32+h];
      }
      float uu = 1.f / (1.f + expf(-(sg + ebg[h])));
      H[((size_t)(b*80) + n)*12*32 + (size_t)c*32 + h] = uu * tanhf(sc + ebc[h]);
    }
  }
}

// ---------------------------------------------------------------- generic GRU-cell bdg kernel
// Exact R9 structure (256 threads, MT=2, grid (40,8), Gcol staged in LDS, float4
// phase-3 LDS reads, direct global U loads in phase-1).
// MODE 0 (HOUT=64): outA=sigmoid(g[:32]) (update), outB=sigmoid(g[32:])*H (reset*H).
// MODE 1 (HOUT=32): outA=(1-upd)*H+upd*tanh(g); optional fused out-projection.
template<int HOUT, int MODE, bool HAS_U2, bool HAS_FIELD, bool DO_PROJ>
__global__ __launch_bounds__(256) void k_cell(
    const float* __restrict__ U1, const float* __restrict__ W1p,
    const float* __restrict__ U2, const float* __restrict__ W2p,
    const float* __restrict__ field, int fbs,
    const float* __restrict__ bias,
    const float* __restrict__ Gsd, const float* __restrict__ Gs2d, const float* __restrict__ Gcd,
    const float* Hbuf, const float* updbuf,
    float* outA, float* outB,
    const float* __restrict__ w12p, const float* __restrict__ c0p,
    float* projp, int step)
{
  constexpr int MT = 2;
  constexpr int NG = 256 / HOUT;          // pair groups per pass (4 or 8)
  constexpr int NP = (MT*12) / NG;        // passes (6 or 3)
  const int t = threadIdx.x;
  const int b = blockIdx.y;
  const int m0 = blockIdx.x * MT;
  __shared__ float fA[3*MT*384];          // [kn][m][c][l]
  __shared__ float fB[3*MT*384];          // [kn][m][d][l]  (·Gc)
  __shared__ float Gcol[320];             // [lev][mg][n]
  const int mg = t >> 7;                  // local m (0..1)
  const int u  = t & 127;
  const int c0 = u >> 5;                  // 0..3
  const int l  = u & 31;
  const int h  = t % HOUT;
  const int pg = t / HOUT;
  int bofs[NP];
#pragma unroll
  for (int p = 0; p < NP; ++p) bofs[p] = (p*NG + pg) * 32;
  float outr[NP];
#pragma unroll
  for (int p = 0; p < NP; ++p) outr[p] = 0.f;

  // stage G columns (m0, m0+1) for both Chebyshev levels
  for (int i = t; i < 320; i += 256) {
    int lev = i / 160, r = i % 160, mi = r / 80, n = r % 80;
    Gcol[i] = (lev ? Gs2d : Gsd)[n*80 + m0 + mi];
  }
  __syncthreads();

  const size_t ub_base = (size_t)b*80*12*32;
  const int nrounds = HAS_U2 ? 2 : 1;
  for (int rnd = 0; rnd < nrounds; ++rnd) {
    const float* U  = rnd ? U2 : U1;
    const float* Wp = rnd ? W2p : W1p;
    if (rnd) __syncthreads();            // protect LDS: prior phase-3 readers done
    // ---- phase 1: mode-1 diffusion over N into registers (G from LDS broadcast)
    float a0[3], a1[3], a2[3];
#pragma unroll
    for (int j = 0; j < 3; ++j) { a1[j] = 0.f; a2[j] = 0.f; }
    const float* Ub = U + ub_base;
    for (int n = 0; n < 80; ++n) {
      float g1 = Gcol[mg*80 + n];
      float g2 = Gcol[160 + mg*80 + n];
#pragma unroll
      for (int j = 0; j < 3; ++j) {
        float x = Ub[(n*12 + c0 + 4*j)*32 + l];
        a1[j] += g1*x; a2[j] += g2*x;
      }
    }
#pragma unroll
    for (int j = 0; j < 3; ++j) a0[j] = Ub[((m0+mg)*12 + c0 + 4*j)*32 + l];
#pragma unroll
    for (int j = 0; j < 3; ++j) {
      int cc = c0 + 4*j;
      fA[(0*MT+mg)*384 + cc*32 + l] = a0[j];
      fA[(1*MT+mg)*384 + cc*32 + l] = a1[j];
      fA[(2*MT+mg)*384 + cc*32 + l] = a2[j];
    }
    __syncthreads();
    // ---- phase 2: mode-2 (·Gc along C)
    for (int idx = t; idx < 3*MT*384; idx += 256) {
      int ll = idx & 31;
      int d  = (idx >> 5) % 12;
      int km = idx / 384;
      float s = 0.f;
#pragma unroll
      for (int c = 0; c < 12; ++c) s += fA[km*384 + c*32 + ll] * Gcd[c*12 + d];
      fB[km*384 + d*32 + ll] = s;
    }
    __syncthreads();
    // ---- phase 3: feat @ Wp (register-blocked over NP pairs, float4 LDS reads)
    for (int f = 0; f < 6; ++f) {
      int kn = f >> 1;
      const float* src = ((f & 1) ? fB : fA) + kn*MT*384;
#pragma unroll
      for (int l4 = 0; l4 < 8; ++l4) {
        const float w0 = Wp[(f*32 + l4*4 + 0)*HOUT + h];
        const float w1 = Wp[(f*32 + l4*4 + 1)*HOUT + h];
        const float w2 = Wp[(f*32 + l4*4 + 2)*HOUT + h];
        const float w3 = Wp[(f*32 + l4*4 + 3)*HOUT + h];
#pragma unroll
        for (int p = 0; p < NP; ++p) {
          const float4 v = *(const float4*)&src[bofs[p] + l4*4];
          outr[p] += v.x*w0 + v.y*w1 + v.z*w2 + v.w*w3;
        }
      }
    }
  }
  // ---- epilogue
#pragma unroll
  for (int p = 0; p < NP; ++p) {
    int pair = p*NG + pg;
    int m = pair / 12, c = pair % 12;
    int n = m0 + m;
    size_t oidx = (size_t)(b*80 + n)*12 + c;
    float g = outr[p] + bias[h];
    if (HAS_FIELD) g += field[(size_t)b*fbs + (size_t)(n*12 + c)*HOUT + h];
    if (MODE == 0) {
      float sg = 1.f / (1.f + expf(-g));
      size_t hb = oidx*32;
      if (h < 32) outA[hb + h] = sg;                               // update
      else        outB[hb + (h-32)] = sg * Hbuf[hb + (h-32)];      // reset*H
    } else {
      float cd = tanhf(g);
      size_t hi = oidx*32 + h;
      float uu = updbuf[hi];
      float hv = Hbuf[hi];
      float hn = (1.f - uu)*hv + uu*cd;
      outA[hi] = hn;
      if (DO_PROJ) {
        float pv = hn * w12p[h];
        for (int off = 16; off; off >>= 1) pv += __shfl_down(pv, off, 32);
        if (h == 0) projp[((size_t)(b*6 + step)*80 + n)*12 + c] = pv + c0p[0];
      }
    }
  }
}

// ================================================================= host
extern "C" void kernel_launch(void* const* d_in, const int* in_sizes, int n_in,
                              void* d_out, int out_size, void* d_ws, size_t ws_size,
                              hipStream_t stream) {
  (void)in_sizes; (void)n_in; (void)out_size;
  const float* X    = (const float*)d_in[0];
  const float* As   = (const float*)d_in[1];
  const float* Ac   = (const float*)d_in[2];
  const float* WuS  = (const float*)d_in[3];
  const float* WvS  = (const float*)d_in[4];
  const float* WuC  = (const float*)d_in[5];
  const float* WvC  = (const float*)d_in[6];
  const float* WA_S = (const float*)d_in[7];
  const float* bA_S = (const float*)d_in[8];
  const float* WP_S = (const float*)d_in[9];
  const float* bP_S = (const float*)d_in[10];
  const float* WA_C = (const float*)d_in[11];
  const float* bA_C = (const float*)d_in[12];
  const float* WP_C = (const float*)d_in[13];
  const float* bP_C = (const float*)d_in[14];
  const float* eWg  = (const float*)d_in[15];
  const float* ebg  = (const float*)d_in[16];
  const float* eWc  = (const float*)d_in[17];
  const float* ebc  = (const float*)d_in[18];
  const float* dWg  = (const float*)d_in[19];
  const float* dbg  = (const float*)d_in[20];
  const float* dWc  = (const float*)d_in[21];
  const float* dbc  = (const float*)d_in[22];
  const float* W1   = (const float*)d_in[23];
  const float* b1   = (const float*)d_in[24];
  const float* W2   = (const float*)d_in[25];
  const float* b2   = (const float*)d_in[26];
  float* out = (float*)d_out;

  float* w = (float*)d_ws;
  size_t o = 0;
  auto alloc = [&](size_t n) { float* p = w + o; o += (n + 63) & ~(size_t)63; return p; };
  float* Us     = alloc(245760);
  float* Vs     = alloc(245760);
  float* Uc     = alloc(36864);
  float* Vc     = alloc(36864);
  float* Mb     = alloc(6400);
  float* Mc     = alloc(144);
  float* Ps     = alloc(6400);
  float* Pc     = alloc(144);
  float* part   = alloc((size_t)64*6400);
  float* Gs     = alloc(6400);
  float* Gc     = alloc(144);
  float* Gs2    = alloc(6400);
  float* encWgh = alloc(192*64);
  float* encWch = alloc(192*32);
  float* WgX    = alloc(384);
  float* WcX    = alloc(192);
  float* decWgc = alloc(192*64);
  float* decWcx = alloc(192*32);
  float* decWch = alloc(192*32);
  float* w12    = alloc(32);
  float* c0     = alloc(64);
  float* H      = alloc(245760);
  float* H2     = alloc(245760);
  float* upd    = alloc(245760);
  float* rH     = alloc(245760);
  float* gXg    = alloc((size_t)5898240);
  float* gXc    = alloc((size_t)2949120);
  if (o * sizeof(float) > ws_size) return;   // insufficient scratch -> fail loudly

  k_pack<<<1,256,0,stream>>>(eWg, eWc, dWg, dWc, W1, b1, W2, b2,
                             encWgh, encWch, WgX, WcX, decWgc, decWcx, decWch, w12, c0);
  k_uv<<<1104,256,0,stream>>>(X, WuS, WvS, WuC, WvC, Us, Vs, Uc, Vc);
  // M/Mc: r-split partials (156 blocks, occupancy fix for the 93us latency-bound k_m_mc)
  k_m_mc_part<<<dim3(26,6),256,0,stream>>>(Us, Vs, Uc, Vc, part);
  k_mred<<<26,256,0,stream>>>(part, Mb, Mc);
  k_softmax2<<<92,64,0,stream>>>(Mb, Ps, Mc, Pc);
  k_fus_partial<<<dim3(25,64),dim3(64,4),0,stream>>>(As, Ps, WA_S, WP_S, part);
  k_final2<<<26,256,0,stream>>>(part, bA_S, bP_S, As, Ps, Gs,
                                Ac, Pc, WA_C, WP_C, bA_C, bP_C, Gc);
  k_cheby<<<25,256,0,stream>>>(Gs, Gs2);
  // k_gx also computes encoder step-0 H in its t==0 blocks (replaces k_cell0 + H memset)
  k_gx<<<dim3(96,4),256,0,stream>>>(X, Gs, Gs2, Gc, WgX, WcX, ebg, ebc, gXg, gXc, H);

  // encoder steps 1..11: H updated in place (cand reads H only pointwise)
  for (int t = 1; t < 12; ++t) {
    k_cell<64,0,false,true,false><<<dim3(40,8),256,0,stream>>>(
        H, encWgh, nullptr, nullptr, gXg + (size_t)t*61440, 737280, ebg,
        Gs, Gs2, Gc, H, nullptr, upd, rH, nullptr, nullptr, nullptr, 0);
    k_cell<32,1,false,true,false><<<dim3(40,8),256,0,stream>>>(
        rH, encWch, nullptr, nullptr, gXc + (size_t)t*30720, 368640, ebc,
        Gs, Gs2, Gc, H, upd, H, nullptr, nullptr, nullptr, nullptr, 0);
  }
  // decoder: 6 steps, Xin == H (combined gate weights), ping-pong buffers
  float* Hd = H; float* Hn = H2;
  for (int i = 0; i < 6; ++i) {
    k_cell<64,0,false,false,false><<<dim3(40,8),256,0,stream>>>(
        Hd, decWgc, nullptr, nullptr, nullptr, 0, dbg,
        Gs, Gs2, Gc, Hd, nullptr, upd, rH, nullptr, nullptr, nullptr, 0);
    k_cell<32,1,true,false,true><<<dim3(40,8),256,0,stream>>>(
        Hd, decWcx, rH, decWch, nullptr, 0, dbc,
        Gs, Gs2, Gc, Hd, upd, Hn, nullptr, w12, c0, out, i);
    float* tmp = Hd; Hd = Hn; Hn = tmp;
  }
}